// Round 4
// baseline (76.867 us; speedup 1.0000x reference)
//
#include <hip/hip_runtime.h>

// DIAGNOSTIC ROUND: R2's monolithic kernel, launched TWICE back-to-back.
// dur_us(R4) - dur_us(R2) = one kernel's true duration M, independent of the
// harness reset cost C (the ~42us d_ws poison fill dominates dur_us and hides
// M; our dispatches never appear in rocprof top-5, so M < 40us is otherwise
// unobservable). Second launch is idempotent: res[] is rebuilt from -q each
// launch, out rewritten with identical values (fp-atomic order jitter << thr).
//
// FM second-order term via f16 MFMA:
//   out[b] = sum_e (sum_f x[b,f]*W[f,e])^2 - sum_f x[b,f]^2 * s[f]
// W pre-scaled by 2^13 (exact), y'^2 rescaled by 2^-26; q-term fp32.

constexpr int F  = 200;
constexpr int RB = 32;              // rows per block
constexpr int KP = 232;             // fp16 row stride
constexpr float WSCALE = 8192.0f;   // 2^13
constexpr float OSCALE = 1.0f / (WSCALE * WSCALE);  // 2^-26

typedef _Float16 half8 __attribute__((ext_vector_type(8)));
typedef _Float16 half4 __attribute__((ext_vector_type(4)));
typedef float floatx4 __attribute__((ext_vector_type(4)));

__global__ __launch_bounds__(256)
void fm_mfma(const float* __restrict__ X, const float* __restrict__ W,
             float* __restrict__ out)
{
    __shared__ alignas(16) _Float16 xt[RB][KP];   // 14.8 KB
    __shared__ alignas(16) _Float16 wt[64][KP];   // 29.7 KB
    __shared__ alignas(16) float    sf[F];
    __shared__ alignas(16) float    res[RB];

    const int t    = threadIdx.x;
    const int lane = t & 63;

    // ---------------- phase 1: W -> wt (transposed, scaled fp16) + s[f] ----
    {
        const floatx4* W4 = (const floatx4*)W;    // 3200 float4, [f][e]
        for (int j = 0; j < 13; ++j) {
            int i = t + 256 * j;
            if (i < 3200) {
                floatx4 w4 = W4[i];
                int f  = i >> 4;
                int e0 = (i & 15) * 4;
                float ss = w4.x*w4.x + w4.y*w4.y + w4.z*w4.z + w4.w*w4.w;
                ss += __shfl_xor(ss, 1, 64);
                ss += __shfl_xor(ss, 2, 64);
                ss += __shfl_xor(ss, 4, 64);
                ss += __shfl_xor(ss, 8, 64);
                if ((t & 15) == 0) sf[f] = ss;
                wt[e0 + 0][f] = (_Float16)(w4.x * WSCALE);
                wt[e0 + 1][f] = (_Float16)(w4.y * WSCALE);
                wt[e0 + 2][f] = (_Float16)(w4.z * WSCALE);
                wt[e0 + 3][f] = (_Float16)(w4.w * WSCALE);
            }
        }
        half8 z = {};
        *(half8*)&wt[t >> 2][200 + 8 * (t & 3)] = z;
        if (t < 128) *(half8*)&xt[t >> 2][200 + 8 * (t & 3)] = z;
    }
    __syncthreads();

    // ---------------- phase 2: X -> xt (fp16) + q (fp32) -------------------
    const int rowBase = (int)blockIdx.x * RB;
    {
        int r = t >> 3, sub = t & 7;
        const floatx4* Xr = (const floatx4*)(X + (size_t)(rowBase + r) * F);
        float q = 0.f;
        for (int j = 0; j < 7; ++j) {
            int f4 = sub + 8 * j;
            if (f4 < 50) {
                floatx4 x4 = Xr[f4];
                floatx4 s4 = *(const floatx4*)&sf[4 * f4];
                q += x4.x*x4.x*s4.x + x4.y*x4.y*s4.y + x4.z*x4.z*s4.z + x4.w*x4.w*s4.w;
                half4 h;
                h[0] = (_Float16)x4.x; h[1] = (_Float16)x4.y;
                h[2] = (_Float16)x4.z; h[3] = (_Float16)x4.w;
                *(half4*)&xt[r][4 * f4] = h;
            }
        }
        q += __shfl_xor(q, 1, 64);
        q += __shfl_xor(q, 2, 64);
        q += __shfl_xor(q, 4, 64);
        if (sub == 0) res[r] = -q;
    }
    __syncthreads();

    // ---------------- phase 3: MFMA y' = xt @ wt^T, epilogue ----------------
    {
        const int w  = t >> 6;
        const int mt = (w & 1) * 16;
        const int nb = (w >> 1) * 32;
        const int lm = lane & 15, lq = lane >> 4;

        const half8* ap  = (const half8*)&xt[mt + lm][lq * 8];
        const half8* b0p = (const half8*)&wt[nb + lm][lq * 8];
        const half8* b1p = (const half8*)&wt[nb + 16 + lm][lq * 8];

        floatx4 acc0 = {}, acc1 = {};
        #pragma unroll
        for (int kk = 0; kk < 7; ++kk) {
            half8 a  = ap [kk * 4];
            half8 b0 = b0p[kk * 4];
            half8 b1 = b1p[kk * 4];
            acc0 = __builtin_amdgcn_mfma_f32_16x16x32_f16(a, b0, acc0, 0, 0, 0);
            acc1 = __builtin_amdgcn_mfma_f32_16x16x32_f16(a, b1, acc1, 0, 0, 0);
        }

        float p[4];
        #pragma unroll
        for (int r2 = 0; r2 < 4; ++r2)
            p[r2] = acc0[r2]*acc0[r2] + acc1[r2]*acc1[r2];
        #pragma unroll
        for (int r2 = 0; r2 < 4; ++r2) {
            p[r2] += __shfl_xor(p[r2], 1, 64);
            p[r2] += __shfl_xor(p[r2], 2, 64);
            p[r2] += __shfl_xor(p[r2], 4, 64);
            p[r2] += __shfl_xor(p[r2], 8, 64);
        }
        if (lm == 0) {
            #pragma unroll
            for (int r2 = 0; r2 < 4; ++r2)
                atomicAdd(&res[mt + lq * 4 + r2], p[r2] * OSCALE);
        }
    }
    __syncthreads();

    if (t < RB) out[rowBase + t] = res[t];
}

extern "C" void kernel_launch(void* const* d_in, const int* in_sizes, int n_in,
                              void* d_out, int out_size, void* d_ws, size_t ws_size,
                              hipStream_t stream) {
    const float* X = (const float*)d_in[0];   // [16384, 200] fp32
    const float* W = (const float*)d_in[1];   // [200, 64] fp32
    float* out = (float*)d_out;               // [16384, 1] fp32

    const int B = in_sizes[0] / F;            // 16384
    // Launch TWICE: dur_us(this) - dur_us(R2) = one kernel's duration M.
    fm_mfma<<<B / RB, 256, 0, stream>>>(X, W, out);
    fm_mfma<<<B / RB, 256, 0, stream>>>(X, W, out);
}

// Round 5
// 68.347 us; speedup vs baseline: 1.1247x; 1.1247x over previous
//
#include <hip/hip_runtime.h>

// FM second-order term, single kernel, no W transpose:
//   out[b] = sum_e (sum_f x[b,f]*W[f,e])^2 - sum_f x[b,f]^2 * s[f]
// y = x@W via mfma_f32_16x16x32_f16. B-fragments (B[k][n] = W[f][e]) are
// loaded DIRECTLY from W's natural [f][e] layout into registers (8 strided
// dwords per k-step; each instr = 4 x 64B contiguous segments in L2) -- the
// per-block LDS transpose (8-way-conflict b16 scatter) of R2 is gone.
// W pre-scaled 2^13 (fp16 range), y'^2 rescaled 2^-26; q-term fp32.
// B=16384, F=200 (K padded to 224), E=64. Grid 512 x 256, RB=32.

constexpr int F  = 200;
constexpr int E  = 64;
constexpr int RB = 32;              // rows per block
constexpr int KP = 232;             // xt fp16 row stride (464 B, b128-aligned)
constexpr float WSCALE = 8192.0f;   // 2^13 (exact)
constexpr float OSCALE = 1.0f / (WSCALE * WSCALE);  // 2^-26 (exact)

typedef _Float16 half8 __attribute__((ext_vector_type(8)));
typedef _Float16 half4 __attribute__((ext_vector_type(4)));
typedef float floatx4 __attribute__((ext_vector_type(4)));

__global__ __launch_bounds__(256)
void fm_v5(const float* __restrict__ X, const float* __restrict__ W,
           float* __restrict__ out)
{
    __shared__ alignas(16) _Float16 xt[RB][KP];   // 14.8 KB
    __shared__ alignas(16) float    sf[F];
    __shared__ alignas(16) float    res[RB];

    const int t    = threadIdx.x;
    const int lane = t & 63;
    const int w    = __builtin_amdgcn_readfirstlane(t >> 6);
    const int rowBase = (int)blockIdx.x * RB;

    // ---- (a) X loads up-front: 8 threads/row, 7 float4 each (coalesced) ----
    const int r = t >> 3, sub = t & 7;
    const floatx4* Xr = (const floatx4*)(X + (size_t)(rowBase + r) * F);
    floatx4 xv[7];
    #pragma unroll
    for (int j = 0; j < 7; ++j) {
        int f4 = sub + 8 * j;                     // 50 float4 per row
        if (f4 < 50) xv[j] = Xr[f4];
        else { floatx4 zz = {}; xv[j] = zz; }
    }

    // ---- (b) B-fragments straight from W (natural [f][e] layout) ----------
    // lane (lm,lq) holds B[k = kk*32 + lq*8 + j][n = w*16 + lm]
    const int lm = lane & 15, lq = lane >> 4;
    const int e  = w * 16 + lm;
    float wraw[7][8];
    #pragma unroll
    for (int kk = 0; kk < 7; ++kk) {
        #pragma unroll
        for (int j = 0; j < 8; ++j) {
            int f = kk * 32 + lq * 8 + j;         // guard real only at kk==6
            wraw[kk][j] = (f < F) ? W[f * E + e] : 0.f;
        }
    }
    half8 bfrag[7];
    #pragma unroll
    for (int kk = 0; kk < 7; ++kk)
        #pragma unroll
        for (int j = 0; j < 8; ++j)
            bfrag[kk][j] = (_Float16)(wraw[kk][j] * WSCALE);

    // ---- (c) s[f] = sum_e W[f,e]^2 : one thread per f, coalesced row dot --
    if (t < F) {
        const floatx4* Wr = (const floatx4*)(W + t * E);
        float s0 = 0.f, s1 = 0.f, s2 = 0.f, s3 = 0.f;
        #pragma unroll
        for (int j = 0; j < 16; j += 4) {
            floatx4 a = Wr[j], b = Wr[j + 1], c = Wr[j + 2], d = Wr[j + 3];
            s0 += a.x*a.x + a.y*a.y + a.z*a.z + a.w*a.w;
            s1 += b.x*b.x + b.y*b.y + b.z*b.z + b.w*b.w;
            s2 += c.x*c.x + c.y*c.y + c.z*c.z + c.w*c.w;
            s3 += d.x*d.x + d.y*d.y + d.z*d.z + d.w*d.w;
        }
        sf[t] = (s0 + s1) + (s2 + s3);
    }
    __syncthreads();                              // sf ready

    // ---- q-term (fp32) + x -> fp16 xt ------------------------------------
    {
        float q = 0.f;
        #pragma unroll
        for (int j = 0; j < 7; ++j) {
            int f4 = sub + 8 * j;
            if (f4 < 50) {
                floatx4 x4 = xv[j];
                floatx4 s4 = *(const floatx4*)&sf[4 * f4];
                q += x4.x*x4.x*s4.x + x4.y*x4.y*s4.y + x4.z*x4.z*s4.z + x4.w*x4.w*s4.w;
                half4 h;
                h[0] = (_Float16)x4.x; h[1] = (_Float16)x4.y;
                h[2] = (_Float16)x4.z; h[3] = (_Float16)x4.w;
                *(half4*)&xt[r][4 * f4] = h;
            }
        }
        q += __shfl_xor(q, 1, 64);
        q += __shfl_xor(q, 2, 64);
        q += __shfl_xor(q, 4, 64);
        if (sub == 0) res[r] = -q;
        half8 z = {};
        if (t < 128) *(half8*)&xt[t >> 2][200 + 8 * (t & 3)] = z;  // pad [200,232)
    }
    __syncthreads();                              // xt + res ready

    // ---- MFMA: wave w = n-tile e[16w,16w+16), two m-tiles (rows 0-15,16-31)
    {
        const half8* a0 = (const half8*)&xt[lm][lq * 8];        // m-tile 0
        const half8* a1 = (const half8*)&xt[16 + lm][lq * 8];   // m-tile 1
        floatx4 acc0 = {}, acc1 = {};
        #pragma unroll
        for (int kk = 0; kk < 7; ++kk) {          // K = 7*32 = 224
            acc0 = __builtin_amdgcn_mfma_f32_16x16x32_f16(a0[kk * 4], bfrag[kk], acc0, 0, 0, 0);
            acc1 = __builtin_amdgcn_mfma_f32_16x16x32_f16(a1[kk * 4], bfrag[kk], acc1, 0, 0, 0);
        }

        // C/D: lane (lm,lq), reg r2 -> row lq*4+r2 (+0/16), col = n (reduced)
        float p0[4], p1[4];
        #pragma unroll
        for (int r2 = 0; r2 < 4; ++r2) {
            p0[r2] = acc0[r2] * acc0[r2];
            p1[r2] = acc1[r2] * acc1[r2];
        }
        #pragma unroll
        for (int r2 = 0; r2 < 4; ++r2) {          // sum over 16 cols (lm)
            p0[r2] += __shfl_xor(p0[r2], 1, 64);
            p0[r2] += __shfl_xor(p0[r2], 2, 64);
            p0[r2] += __shfl_xor(p0[r2], 4, 64);
            p0[r2] += __shfl_xor(p0[r2], 8, 64);
            p1[r2] += __shfl_xor(p1[r2], 1, 64);
            p1[r2] += __shfl_xor(p1[r2], 2, 64);
            p1[r2] += __shfl_xor(p1[r2], 4, 64);
            p1[r2] += __shfl_xor(p1[r2], 8, 64);
        }
        if (lm == 0) {
            #pragma unroll
            for (int r2 = 0; r2 < 4; ++r2) {
                atomicAdd(&res[lq * 4 + r2],      p0[r2] * OSCALE);
                atomicAdd(&res[16 + lq * 4 + r2], p1[r2] * OSCALE);
            }
        }
    }
    __syncthreads();

    if (t < RB) out[rowBase + t] = res[t];
}

extern "C" void kernel_launch(void* const* d_in, const int* in_sizes, int n_in,
                              void* d_out, int out_size, void* d_ws, size_t ws_size,
                              hipStream_t stream) {
    const float* X = (const float*)d_in[0];   // [16384, 200] fp32
    const float* W = (const float*)d_in[1];   // [200, 64] fp32
    float* out = (float*)d_out;               // [16384, 1] fp32

    const int B = in_sizes[0] / F;            // 16384
    fm_v5<<<B / RB, 256, 0, stream>>>(X, W, out);
}

// Round 6
// 67.299 us; speedup vs baseline: 1.1422x; 1.0156x over previous
//
#include <hip/hip_runtime.h>

// FM second-order term, single kernel, 2 barriers, RB=64:
//   out[b] = sum_e (sum_f x[b,f]*W[f,e])^2 - sum_f x[b,f]^2 * s[f]
// Phase 1 (merged): issue X float4 loads; W->wt fp16 transpose (+2^13 scale)
//   + s[f] via shfl; x->fp16 xt.   barrier.
// Phase 2: q (fp32, staging distribution) -> res[r] = -q;  MFMA: wave w owns
//   rows [16w,16w+16) x ALL 4 n-tiles (28 mfma, 4 accs).   barrier.
// Epilogue: p = sum_e y'^2 (shfl over 16 cols), single-writer combine with
//   res, DIRECT global stores (no atomics, no 3rd barrier).
// B=16384, F=200 (K padded 224), E=64. Grid 256 x 256.

constexpr int F  = 200;
constexpr int RB = 64;              // rows per block
constexpr int KP = 232;             // fp16 row stride (29 half8; ~2-way banks)
constexpr float WSCALE = 8192.0f;   // 2^13 (exact)
constexpr float OSCALE = 1.0f / (WSCALE * WSCALE);  // 2^-26 (exact)

typedef _Float16 half8 __attribute__((ext_vector_type(8)));
typedef _Float16 half4 __attribute__((ext_vector_type(4)));
typedef float floatx4 __attribute__((ext_vector_type(4)));

__global__ __launch_bounds__(256)
void fm_v6(const float* __restrict__ X, const float* __restrict__ W,
           float* __restrict__ out)
{
    __shared__ alignas(16) _Float16 wt[64][KP];   // 29.7 KB  W^T * 2^13
    __shared__ alignas(16) _Float16 xt[RB][KP];   // 29.7 KB  x fp16
    __shared__ alignas(16) float    sf[F];        // s[f]
    __shared__ alignas(16) float    res[RB];      // -q per row

    const int t    = threadIdx.x;
    const int lane = t & 63;
    const int w    = __builtin_amdgcn_readfirstlane(t >> 6);
    const int rowBase = (int)blockIdx.x * RB;

    // ---- phase 1a: issue X loads (4 threads/row, 64 rows, 50 float4/row) --
    const int r = t >> 2, sub = t & 3;
    const floatx4* Xr = (const floatx4*)(X + (size_t)(rowBase + r) * F);
    floatx4 xv[13];
    #pragma unroll
    for (int j = 0; j < 13; ++j) {
        int f4 = sub + 4 * j;
        if (f4 < 50) xv[j] = Xr[f4];
    }

    // ---- phase 1b: W -> wt transpose (+scale) and s[f] (fills X shadow) ---
    {
        const floatx4* W4 = (const floatx4*)W;    // 3200 float4, [f][e]
        for (int j = 0; j < 13; ++j) {
            int i = t + 256 * j;
            if (i < 3200) {
                floatx4 w4 = W4[i];
                int f  = i >> 4;                  // 16 float4 per f-row
                int e0 = (i & 15) * 4;
                float ss = w4.x*w4.x + w4.y*w4.y + w4.z*w4.z + w4.w*w4.w;
                ss += __shfl_xor(ss, 1, 64);
                ss += __shfl_xor(ss, 2, 64);
                ss += __shfl_xor(ss, 4, 64);
                ss += __shfl_xor(ss, 8, 64);
                if ((t & 15) == 0) sf[f] = ss;
                wt[e0 + 0][f] = (_Float16)(w4.x * WSCALE);
                wt[e0 + 1][f] = (_Float16)(w4.y * WSCALE);
                wt[e0 + 2][f] = (_Float16)(w4.z * WSCALE);
                wt[e0 + 3][f] = (_Float16)(w4.w * WSCALE);
            }
        }
        half8 z = {};
        *(half8*)&wt[t >> 2][200 + 8 * (t & 3)] = z;   // pad [200,232), 64 rows
        *(half8*)&xt[t >> 2][200 + 8 * (t & 3)] = z;   // pad, 64 rows (RB=64)
    }

    // ---- phase 1c: x -> fp16 xt ------------------------------------------
    #pragma unroll
    for (int j = 0; j < 13; ++j) {
        int f4 = sub + 4 * j;
        if (f4 < 50) {
            floatx4 x4 = xv[j];
            half4 h;
            h[0] = (_Float16)x4.x; h[1] = (_Float16)x4.y;
            h[2] = (_Float16)x4.z; h[3] = (_Float16)x4.w;
            *(half4*)&xt[r][4 * f4] = h;
        }
    }
    __syncthreads();                              // barrier 1: wt/sf/xt ready

    // ---- phase 2a: q (fp32, staging distribution); sf reads broadcast ----
    {
        float q = 0.f;
        #pragma unroll
        for (int j = 0; j < 13; ++j) {
            int f4 = sub + 4 * j;
            if (f4 < 50) {
                floatx4 x4 = xv[j];
                floatx4 s4 = *(const floatx4*)&sf[4 * f4];
                q += x4.x*x4.x*s4.x + x4.y*x4.y*s4.y + x4.z*x4.z*s4.z + x4.w*x4.w*s4.w;
            }
        }
        q += __shfl_xor(q, 1, 64);                // reduce over 4 sub-lanes
        q += __shfl_xor(q, 2, 64);
        if (sub == 0) res[r] = -q;
    }

    // ---- phase 2b: MFMA — wave w: rows [16w,16w+16), ALL 4 n-tiles --------
    const int lm = lane & 15, lq = lane >> 4;
    floatx4 acc0 = {}, acc1 = {}, acc2 = {}, acc3 = {};
    {
        const half8* ap = (const half8*)&xt[16 * w + lm][lq * 8];
        const half8* b0 = (const half8*)&wt[ 0 + lm][lq * 8];
        const half8* b1 = (const half8*)&wt[16 + lm][lq * 8];
        const half8* b2 = (const half8*)&wt[32 + lm][lq * 8];
        const half8* b3 = (const half8*)&wt[48 + lm][lq * 8];
        #pragma unroll
        for (int kk = 0; kk < 7; ++kk) {          // K = 224; +32 halfs = 4 half8
            half8 a = ap[kk * 4];
            acc0 = __builtin_amdgcn_mfma_f32_16x16x32_f16(a, b0[kk * 4], acc0, 0, 0, 0);
            acc1 = __builtin_amdgcn_mfma_f32_16x16x32_f16(a, b1[kk * 4], acc1, 0, 0, 0);
            acc2 = __builtin_amdgcn_mfma_f32_16x16x32_f16(a, b2[kk * 4], acc2, 0, 0, 0);
            acc3 = __builtin_amdgcn_mfma_f32_16x16x32_f16(a, b3[kk * 4], acc3, 0, 0, 0);
        }
    }
    __syncthreads();                              // barrier 2: res (-q) ready

    // ---- epilogue: p = sum_e y'^2, single-writer combine, direct stores ---
    {
        float p[4];
        #pragma unroll
        for (int r2 = 0; r2 < 4; ++r2)
            p[r2] = acc0[r2]*acc0[r2] + acc1[r2]*acc1[r2]
                  + acc2[r2]*acc2[r2] + acc3[r2]*acc3[r2];
        #pragma unroll
        for (int r2 = 0; r2 < 4; ++r2) {          // sum over 16 cols (lm)
            p[r2] += __shfl_xor(p[r2], 1, 64);
            p[r2] += __shfl_xor(p[r2], 2, 64);
            p[r2] += __shfl_xor(p[r2], 4, 64);
            p[r2] += __shfl_xor(p[r2], 8, 64);
        }
        if (lm == 0) {
            #pragma unroll
            for (int r2 = 0; r2 < 4; ++r2) {
                int row = 16 * w + lq * 4 + r2;   // C/D: row = lq*4 + r2
                out[rowBase + row] = fmaf(p[r2], OSCALE, res[row]);
            }
        }
    }
}

extern "C" void kernel_launch(void* const* d_in, const int* in_sizes, int n_in,
                              void* d_out, int out_size, void* d_ws, size_t ws_size,
                              hipStream_t stream) {
    const float* X = (const float*)d_in[0];   // [16384, 200] fp32
    const float* W = (const float*)d_in[1];   // [200, 64] fp32
    float* out = (float*)d_out;               // [16384, 1] fp32

    const int B = in_sizes[0] / F;            // 16384
    fm_v6<<<B / RB, 256, 0, stream>>>(X, W, out);
}